// Round 8
// baseline (2499.880 us; speedup 1.0000x reference)
//
#include <hip/hip_runtime.h>

typedef __attribute__((ext_vector_type(8))) short short8;
typedef __attribute__((ext_vector_type(4))) float f32x4;
typedef __attribute__((ext_vector_type(2))) float f32x2;
typedef __attribute__((ext_vector_type(4))) unsigned short us4;
typedef __attribute__((ext_vector_type(2))) unsigned int u32x2;

__device__ __forceinline__ unsigned short bf16_of(float f) {
    unsigned u = __builtin_bit_cast(unsigned, f);
    u += 0x7fffu + ((u >> 16) & 1u);   // RNE
    return (unsigned short)(u >> 16);
}
__device__ __forceinline__ unsigned bf16pk(float a, float b) {
    return (unsigned)bf16_of(a) | ((unsigned)bf16_of(b) << 16);
}
__device__ __forceinline__ float fexp2(float x) { return __builtin_amdgcn_exp2f(x); }
__device__ __forceinline__ float frcp(float x) { return __builtin_amdgcn_rcpf(x); }
__device__ __forceinline__ float sigm(float x) { return frcp(1.f + fexp2(-1.44269504f * x)); }
__device__ __forceinline__ float tanh_f(float x) {
    float e = fexp2(2.88539008f * x);   // e^(2x)
    return 1.f - 2.f * frcp(e + 1.f);
}
__device__ __forceinline__ f32x4 mfma16(short8 a, short8 b, f32x4 c) {
    return __builtin_amdgcn_mfma_f32_16x16x32_bf16(a, b, c, 0, 0, 0);
}
// DPP cross-lane within 16-lane rows. row_shr:8 -> lane i gets lane i-8;
// row_shl:8 -> lane i gets lane i+8 (bound_ctrl: OOB reads 0).
__device__ __forceinline__ float dpp_shr8(float x) {
    return __builtin_bit_cast(float, __builtin_amdgcn_update_dpp(
        0, __builtin_bit_cast(int, x), 0x118, 0xF, 0xF, true));
}
__device__ __forceinline__ float dpp_shl8(float x) {
    return __builtin_bit_cast(float, __builtin_amdgcn_update_dpp(
        0, __builtin_bit_cast(int, x), 0x108, 0xF, 0xF, true));
}

// ---------------------------------------------------------------------------
// Generic fp32 GEMM: C[M,N] = A[M,K] @ B (+bias) (optional relu).
__global__ __launch_bounds__(256) void gemm_f32(
    const float* __restrict__ A, const float* __restrict__ B,
    const float* __restrict__ bias, float* __restrict__ C,
    int M, int N, int K, int RELU)
{
    __shared__ float As[64][33];
    __shared__ float Bs[32][68];
    const int tid = threadIdx.x;
    const int tx = tid & 15, ty = tid >> 4;
    const int m0 = blockIdx.y * 64, n0 = blockIdx.x * 64;
    float acc[4][4];
#pragma unroll
    for (int i = 0; i < 4; ++i)
#pragma unroll
        for (int j = 0; j < 4; ++j) acc[i][j] = 0.f;

    for (int k0 = 0; k0 < K; k0 += 32) {
        __syncthreads();
        {   // stage A 64x32
            const int r = tid >> 2, kk = (tid & 3) * 8;
            const float* src = A + (size_t)(m0 + r) * K + k0 + kk;
            f32x4 v0 = *(const f32x4*)src;
            f32x4 v1 = *(const f32x4*)(src + 4);
#pragma unroll
            for (int e = 0; e < 4; ++e) { As[r][kk + e] = v0[e]; As[r][kk + 4 + e] = v1[e]; }
        }
        {   // stage B 32x64
            const int kk = tid >> 3, nn = (tid & 7) * 8;
            const float* src = B + (size_t)(k0 + kk) * N + n0 + nn;
            f32x4 v0 = *(const f32x4*)src;
            f32x4 v1 = *(const f32x4*)(src + 4);
#pragma unroll
            for (int e = 0; e < 4; ++e) { Bs[kk][nn + e] = v0[e]; Bs[kk][nn + 4 + e] = v1[e]; }
        }
        __syncthreads();
#pragma unroll 8
        for (int k = 0; k < 32; ++k) {
            float a0 = As[ty * 4 + 0][k], a1 = As[ty * 4 + 1][k];
            float a2 = As[ty * 4 + 2][k], a3 = As[ty * 4 + 3][k];
            f32x4 bv = *(const f32x4*)&Bs[k][tx * 4];
#pragma unroll
            for (int j = 0; j < 4; ++j) {
                acc[0][j] += a0 * bv[j]; acc[1][j] += a1 * bv[j];
                acc[2][j] += a2 * bv[j]; acc[3][j] += a3 * bv[j];
            }
        }
    }
    f32x4 bv = *(const f32x4*)&bias[n0 + tx * 4];
#pragma unroll
    for (int i = 0; i < 4; ++i) {
        f32x4 res = {};
#pragma unroll
        for (int j = 0; j < 4; ++j) {
            float v = acc[i][j] + bv[j];
            if (RELU) v = fmaxf(v, 0.f);
            res[j] = v;
        }
        *(f32x4*)&C[(size_t)(m0 + ty * 4 + i) * N + n0 + tx * 4] = res;
    }
}

// ---------------------------------------------------------------------------
// Fused sisj + transpose: per (jt, b) tile of h:
//   si/sj[b*1024+jt*64+r] = h-row dot aW halves; hT[b][d][j] = bf16(h[b][j][d])
__global__ __launch_bounds__(256) void aux_k(
    const float* __restrict__ h, const float* __restrict__ aW,
    float* __restrict__ si, float* __restrict__ sj,
    unsigned short* __restrict__ hT)
{
    __shared__ float t[64][129];
    __shared__ float awl[256];
    const int jt = blockIdx.x, b = blockIdx.y;
    const int tid = threadIdx.x;
    awl[tid] = aW[tid];
    {
        const int r = tid >> 2, c8 = (tid & 3) * 32;
        const float* src = h + ((size_t)b * 1024 + jt * 64 + r) * 128 + c8;
#pragma unroll
        for (int e = 0; e < 32; e += 4)
            *(f32x4*)&t[r][c8 + e] = *(const f32x4*)(src + e);
    }
    __syncthreads();
    if (tid < 64) {
        float sjp = 0.f, sip = 0.f;
#pragma unroll 8
        for (int d = 0; d < 128; ++d) {
            float v = t[tid][d];
            sjp += v * awl[d];
            sip += v * awl[128 + d];
        }
        si[b * 1024 + jt * 64 + tid] = sip;
        sj[b * 1024 + jt * 64 + tid] = sjp;
    }
    {
        const int d = tid >> 1, j0 = (tid & 1) * 32;
        unsigned short* dst = hT + ((size_t)b * 128 + d) * 1024 + jt * 64 + j0;
#pragma unroll
        for (int j = 0; j < 32; j += 4) {
            u32x2 o;
            o[0] = bf16pk(t[j0 + j][d], t[j0 + j + 1][d]);
            o[1] = bf16pk(t[j0 + j + 2][d], t[j0 + j + 3][d]);
            *(u32x2*)(dst + j) = o;
        }
    }
}

// ---------------------------------------------------------------------------
// out[b,i,d] = sum_j sigmoid(si[i]+sj[j]+ab)*adj[b,i,j]*h[b,j,d]  (opt relu)
__global__ __launch_bounds__(256) void gnn_agg(
    const float* __restrict__ adj, const unsigned short* __restrict__ hT,
    const float* __restrict__ si, const float* __restrict__ sj,
    const float* __restrict__ abp, float* __restrict__ out, int RELU)
{
    __shared__ __align__(16) unsigned short Alds[64 * 40];   // [i][j] stride 40
    __shared__ __align__(16) unsigned short Blds[128 * 40];  // [d][j] stride 40
    const int b = blockIdx.y, it = blockIdx.x;
    const int i0 = it * 64;
    const int tid = threadIdx.x, lane = tid & 63, w = tid >> 6;
    const int quad = lane >> 4, col = lane & 15;
    const float ab = abp[0];
    const float* adjb = adj + (size_t)b * 1024 * 1024;
    const unsigned short* hTb = hT + (size_t)b * 128 * 1024;
    const float* sjb = sj + b * 1024;

    f32x4 acc[8] = {};
    const int ar_ = tid >> 2, ash = (tid & 3) * 8;
    const int br_ = tid >> 1, bsh = (tid & 1) * 16;
    const float sii = si[b * 1024 + i0 + ar_] + ab;

    for (int j0 = 0; j0 < 1024; j0 += 32) {
        __syncthreads();
        {   // stage A: att tile 64x32 (computed on the fly)
            const float* ar = adjb + (size_t)(i0 + ar_) * 1024 + j0 + ash;
            f32x4 av0 = *(const f32x4*)ar;
            f32x4 av1 = *(const f32x4*)(ar + 4);
            float s[8];
#pragma unroll
            for (int e = 0; e < 4; ++e) {
                s[e]     = sigm(sii + sjb[j0 + ash + e])     * av0[e];
                s[4 + e] = sigm(sii + sjb[j0 + ash + 4 + e]) * av1[e];
            }
            u32x2 o0 = {bf16pk(s[0], s[1]), bf16pk(s[2], s[3])};
            u32x2 o1 = {bf16pk(s[4], s[5]), bf16pk(s[6], s[7])};
            unsigned short* al = Alds + ar_ * 40 + ash;
            *(u32x2*)&al[0] = o0;
            *(u32x2*)&al[4] = o1;
        }
        {   // stage B: hT rows d=0..127, 32 j's
            const unsigned short* bsrc = hTb + (size_t)br_ * 1024 + j0 + bsh;
            unsigned short* bl = Blds + br_ * 40 + bsh;
            *(short8*)&bl[0] = *(const short8*)&bsrc[0];
            *(short8*)&bl[8] = *(const short8*)&bsrc[8];
        }
        __syncthreads();
        short8 af = *(const short8*)&Alds[(w * 16 + col) * 40 + quad * 8];
#pragma unroll
        for (int nt = 0; nt < 8; ++nt) {
            short8 bf = *(const short8*)&Blds[(nt * 16 + col) * 40 + quad * 8];
            acc[nt] = mfma16(af, bf, acc[nt]);
        }
    }
    const int ibase = i0 + w * 16 + quad * 4;
#pragma unroll
    for (int nt = 0; nt < 8; ++nt) {
        const int d = nt * 16 + col;
#pragma unroll
        for (int r = 0; r < 4; ++r) {
            float v = acc[nt][r];
            if (RELU) v = fmaxf(v, 0.f);
            out[((size_t)b * 1024 + ibase + r) * 128 + d] = v;
        }
    }
}

// ---------------------------------------------------------------------------
// Prep: transpose+bf16 the 8 head weight matrices to [n][k]; bf16-convert
// l0Wih (already [n][k] row-major); zero flags. 10 blocks.
struct PrepArgs {
    const float* src[8];
    unsigned short* dst[8];
    int N[8];
};
__global__ __launch_bounds__(256) void prep_k(
    PrepArgs pa, const float* __restrict__ Wih0,
    unsigned short* __restrict__ Wih0T, int* flags)
{
    const int m = blockIdx.x;
    const int tid = threadIdx.x;
    if (m < 8) {
        const float* src = pa.src[m];
        unsigned short* dst = pa.dst[m];
        const int N = pa.N[m];
        const int n0 = tid >> 4, kc = (tid & 15) * 8;
        for (int n = n0; n < N; n += 16) {
            unsigned o[4];
#pragma unroll
            for (int e = 0; e < 8; e += 2)
                o[e >> 1] = bf16pk(src[(size_t)(kc + e) * N + n],
                                   src[(size_t)(kc + e + 1) * N + n]);
            *(u32x2*)&dst[n * 128 + kc] = *(u32x2*)&o[0];
            *(u32x2*)&dst[n * 128 + kc + 4] = *(u32x2*)&o[2];
        }
    } else {
        if (m == 8 && tid < 8) flags[tid] = 0;
        const int base = (m - 8) * 32768;
        for (int i = base + tid * 8; i < base + 32768; i += 2048) {
            f32x4 v0 = *(const f32x4*)&Wih0[i];
            f32x4 v1 = *(const f32x4*)&Wih0[i + 4];
            u32x2 o = {bf16pk(v0[0], v0[1]), bf16pk(v0[2], v0[3])};
            u32x2 o2 = {bf16pk(v1[0], v1[1]), bf16pk(v1[2], v1[3])};
            *(u32x2*)&Wih0T[i] = o;
            *(u32x2*)&Wih0T[i + 4] = o2;
        }
    }
}

// ---------------------------------------------------------------------------
// 12-block lstm_pipe: 2-layer LSTM pipeline + fused xw0 build + MLP heads.
//  block 0 producer : layer-0 recurrence -> bf16 hbuf; flags[0] += 1/16 steps
//                     (waits flags[3] per chunk for xw0 availability)
//  block 1 helper   : xw1(chunk) = h0 @ Wih1^T + bias -> 4-slot ring; flags[1]
//  block 2 consumer : layer-1 recurrence off ring -> bf16 out1b; flags[2]
//  block 3 builder  : xw0(chunk) = h3 @ Wih0^T + bias (pack layout); flags[3]
//                     (~1.2 us/chunk vs producer ~15 us/chunk: stays ahead)
//  blocks 4-11      : head workers: `no` head (bufH3) immediately; op/pa/sk
//                     per 128-row strip as flags[2] publishes chunks.
// Per-step barrier = lgkmcnt(0)-only waitcnt + s_barrier builtins (vmcnt
// prefetches stay outstanding). Flag waits are tid0-guarded.

struct HeadArgs {
    const unsigned short* W1T[4];
    const float* b1[4];
    const unsigned short* W2T[4];
    const float* b2[4];
    float* outp[4];       // op, pa, sk, no
};

__device__ __forceinline__ void lstm_epilogue(
    const f32x4 accs[4], f32x4 xv0, f32x4 xv1, float* cst, float* hv, bool lo)
{
    float t0[4], t1[4];
#pragma unroll
    for (int i = 0; i < 4; ++i) {
        float P0 = 0.5f * ((lo ? accs[0][i] : dpp_shr8(accs[1][i])) + xv0[i]);
        float P1r = (lo ? accs[2][i] : dpp_shr8(accs[3][i])) + xv1[i];
        float P1 = lo ? P1r : 0.5f * P1r;
        t0[i] = tanh_f(P0);
        t1[i] = tanh_f(P1);
    }
    float c2[4], og[4];
#pragma unroll
    for (int i = 0; i < 4; ++i) {
        float ig = 0.5f + 0.5f * t0[i];
        float fg = 0.5f + 0.5f * dpp_shl8(t0[i]);
        float gg = t1[i];
        og[i] = 0.5f + 0.5f * dpp_shl8(t1[i]);
        c2[i] = fg * cst[i] + ig * gg;
        cst[i] = c2[i];
    }
    float pc0 = lo ? c2[0] : dpp_shr8(c2[1]);
    float pc1 = lo ? c2[2] : dpp_shr8(c2[3]);
    float tc0 = tanh_f(pc0), tc1 = tanh_f(pc1);
    float th[4] = {tc0, dpp_shl8(tc0), tc1, dpp_shl8(tc1)};
#pragma unroll
    for (int i = 0; i < 4; ++i) hv[i] = og[i] * th[i];
}

// SINK=0: bf16 hbuf [t*1024 + b*128 + h]; SINK=1: bf16 out1b [(t*8+b)*128 + h]
template <int SINK>
__device__ __forceinline__ void lstm_step(
    unsigned short* Hc, unsigned short* Hn, const short8 afr[4][4],
    f32x4 xv0, f32x4 xv1, float* cst, unsigned short* __restrict__ sink,
    int t, int col, int quad, int h4, int b)
{
    short8 bfr[4];
#pragma unroll
    for (int c = 0; c < 4; ++c)
        bfr[c] = *(const short8*)&Hc[col * 136 + c * 32 + quad * 8];
    f32x4 accs[4] = {};
#pragma unroll
    for (int c = 0; c < 4; ++c)
#pragma unroll
        for (int g = 0; g < 4; ++g)
            accs[g] = mfma16(afr[g][c], bfr[c], accs[g]);

    const bool lo = (col < 8);
    float hv[4];
    lstm_epilogue(accs, xv0, xv1, cst, hv, lo);
    if (lo) {
        u32x2 hb = {bf16pk(hv[0], hv[1]), bf16pk(hv[2], hv[3])};
        *(u32x2*)&Hn[b * 136 + h4] = hb;
        if (SINK == 0)
            *(u32x2*)(sink + (size_t)t * 1024 + b * 128 + h4) = hb;
        else
            *(u32x2*)(sink + ((size_t)t * 8 + b) * 128 + h4) = hb;
    }
    __builtin_amdgcn_s_waitcnt(0xC07F);  // lgkmcnt(0) only
    __builtin_amdgcn_s_barrier();
}

// One 128-row strip of a 2-layer MLP head (8 waves / 512 threads).
template <int A32, int LROWS>
__device__ void head_strip(
    const void* __restrict__ Asrc, int row0,
    const unsigned short* __restrict__ W1T, const float* __restrict__ b1,
    const unsigned short* __restrict__ W2T, const float* __restrict__ b2,
    float* __restrict__ outp, int dout, unsigned short* A2, int tid)
{
    const int lane = tid & 63, w = tid >> 6;
    const int quad = lane >> 4, col = lane & 15;
    const int mrow = w * 16 + col;
    f32x4 acc[8] = {};
#pragma unroll
    for (int kc = 0; kc < 4; ++kc) {
        short8 af;
        if (A32) {
            const float* s = (const float*)Asrc + (size_t)(row0 + mrow) * 128 + kc * 32 + quad * 8;
            f32x4 v0 = *(const f32x4*)s, v1 = *(const f32x4*)(s + 4);
            short8 v;
#pragma unroll
            for (int j = 0; j < 4; ++j) {
                v[j] = (short)bf16_of(v0[j]);
                v[4 + j] = (short)bf16_of(v1[j]);
            }
            af = v;
        } else {
            af = *(const short8*)((const unsigned short*)Asrc +
                                  (size_t)(row0 + mrow) * 128 + kc * 32 + quad * 8);
        }
#pragma unroll
        for (int nt = 0; nt < 8; ++nt) {
            short8 bf = *(const short8*)&W1T[(nt * 16 + col) * 128 + kc * 32 + quad * 8];
            acc[nt] = mfma16(af, bf, acc[nt]);
        }
    }
    float b1v[8];
#pragma unroll
    for (int nt = 0; nt < 8; ++nt) b1v[nt] = b1[nt * 16 + col];
    __syncthreads();
#pragma unroll
    for (int nt = 0; nt < 8; ++nt)
#pragma unroll
        for (int i = 0; i < 4; ++i) {
            const int mm = w * 16 + quad * 4 + i;
            A2[mm * 136 + nt * 16 + col] = bf16_of(fmaxf(acc[nt][i] + b1v[nt], 0.f));
        }
    __syncthreads();
    const int ntiles = dout >> 4;
    for (int np = 0; np < ntiles; np += 8) {
        const int nts = (ntiles - np < 8) ? ntiles - np : 8;
        f32x4 acc2[8] = {};
#pragma unroll
        for (int kc = 0; kc < 4; ++kc) {
            short8 a2f = *(const short8*)&A2[mrow * 136 + kc * 32 + quad * 8];
            for (int nt = 0; nt < nts; ++nt) {
                short8 bf = *(const short8*)&W2T[((np + nt) * 16 + col) * 128 + kc * 32 + quad * 8];
                acc2[nt] = mfma16(a2f, bf, acc2[nt]);
            }
        }
        for (int nt = 0; nt < nts; ++nt) {
            const int n = (np + nt) * 16 + col;
            const float bb = b2[n];
#pragma unroll
            for (int i = 0; i < 4; ++i) {
                const int r = row0 + w * 16 + quad * 4 + i;
                size_t off;
                if (LROWS) off = ((size_t)(r & 7) * 1024 + (r >> 3)) * dout + n;
                else       off = (size_t)r * dout + n;
                outp[off] = acc2[nt][i] + bb;
            }
        }
    }
}

__global__ __launch_bounds__(512) void lstm_pipe(
    float* __restrict__ xw0, const unsigned short* __restrict__ Wih0T,
    const float* __restrict__ bih0, const float* __restrict__ bhh0,
    const float* __restrict__ Whh0,
    const float* __restrict__ Wih1, const float* __restrict__ Whh1,
    const float* __restrict__ bih1, const float* __restrict__ bhh1,
    unsigned short* __restrict__ hbuf, float* __restrict__ xw1,
    int* __restrict__ flags, unsigned short* __restrict__ out1b,
    const float* __restrict__ bufH3, HeadArgs ha)
{
    __shared__ __align__(16) unsigned short H[2][16 * 136];
    __shared__ __align__(16) unsigned short A2[128 * 136];
    const int tid = threadIdx.x;
    const int lane = tid & 63;
    const int w = tid >> 6;
    const int quad = lane >> 4;
    const int col = lane & 15;
    const int b = col & 7;
    const int prA = col >> 3;
    const int h4 = w * 16 + quad * 4;

    if (blockIdx.x >= 4) {
        // ---------------- head workers ----------------
        const int wid = blockIdx.x - 4;   // 0..7
        for (int s = wid; s < 64; s += 8)
            head_strip<1, 0>(bufH3, s * 128, ha.W1T[3], ha.b1[3],
                             ha.W2T[3], ha.b2[3], ha.outp[3], 64, A2, tid);
        for (int s = wid; s < 64; s += 8) {
            if (tid == 0) {
                while (__hip_atomic_load(&flags[2], __ATOMIC_ACQUIRE,
                                         __HIP_MEMORY_SCOPE_AGENT) < s + 1)
                    __builtin_amdgcn_s_sleep(16);
            }
            __syncthreads();
            head_strip<0, 1>(out1b, s * 128, ha.W1T[0], ha.b1[0],
                             ha.W2T[0], ha.b2[0], ha.outp[0], 64, A2, tid);
            head_strip<0, 1>(out1b, s * 128, ha.W1T[1], ha.b1[1],
                             ha.W2T[1], ha.b2[1], ha.outp[1], 256, A2, tid);
            head_strip<0, 1>(out1b, s * 128, ha.W1T[2], ha.b1[2],
                             ha.W2T[2], ha.b2[2], ha.outp[2], 128, A2, tid);
        }
        return;
    }

    if (blockIdx.x == 3) {
        // ---------------- builder: xw0 = h3 @ Wih0^T + bias ----------------
        float biasv[32];
#pragma unroll
        for (int nt = 0; nt < 32; ++nt) {
            const int n = nt * 16 + col;
            biasv[nt] = bih0[n] + bhh0[n];
        }
        const int rr = w * 16 + col;              // chunk-local M row
        const int tl = rr >> 3, bb = rr & 7;
        for (int c = 0; c < 64; ++c) {
            short8 af[4];
            const float* as = bufH3 + ((size_t)bb * 1024 + c * 16 + tl) * 128;
#pragma unroll
            for (int kc = 0; kc < 4; ++kc) {
                f32x4 v0 = *(const f32x4*)(as + kc * 32 + quad * 8);
                f32x4 v1 = *(const f32x4*)(as + kc * 32 + quad * 8 + 4);
                short8 v;
#pragma unroll
                for (int j = 0; j < 4; ++j) {
                    v[j] = (short)bf16_of(v0[j]);
                    v[4 + j] = (short)bf16_of(v1[j]);
                }
                af[kc] = v;
            }
#pragma unroll 4
            for (int nt = 0; nt < 32; ++nt) {
                f32x4 acc = {};
#pragma unroll
                for (int kc = 0; kc < 4; ++kc) {
                    short8 bf = *(const short8*)&Wih0T[(nt * 16 + col) * 128 + kc * 32 + quad * 8];
                    acc = mfma16(af[kc], bf, acc);
                }
                const int n = nt * 16 + col;
                const int pr = n >> 7, hh = n & 127;
#pragma unroll
                for (int i = 0; i < 4; ++i) {
                    const int r2 = w * 16 + quad * 4 + i;
                    const int tl2 = r2 >> 3, bb2 = r2 & 7;
                    xw0[(((size_t)(c * 16 + tl2) * 4 + pr) * 8 + bb2) * 128 + hh]
                        = acc[i] + biasv[nt];
                }
            }
            __syncthreads();   // drain stores before publish
            if (tid == 0)
                __hip_atomic_store(&flags[3], c + 1, __ATOMIC_RELEASE,
                                   __HIP_MEMORY_SCOPE_AGENT);
        }
        return;
    }

    if (blockIdx.x == 1) {
        // ---------------- helper: xw1 = h0 @ Wih1^T + bias ----------------
        short8 afrI[4][4];
        f32x4 biasv[4];
#pragma unroll
        for (int g = 0; g < 4; ++g) {
            const int row = g * 128 + w * 16 + col;
#pragma unroll
            for (int c = 0; c < 4; ++c) {
                const float* src = Wih1 + row * 128 + c * 32 + quad * 8;
                short8 v;
#pragma unroll
                for (int j = 0; j < 8; ++j) v[j] = (short)bf16_of(src[j]);
                afrI[g][c] = v;
            }
            const int rb = g * 128 + w * 16 + quad * 4;
            f32x4 b1 = *(const f32x4*)&bih1[rb];
            f32x4 b2 = *(const f32x4*)&bhh1[rb];
#pragma unroll
            for (int e = 0; e < 4; ++e) biasv[g][e] = b1[e] + b2[e];
        }
        for (int k = 0; k < 64; ++k) {
            if (tid == 0) {
                while (__hip_atomic_load(&flags[0], __ATOMIC_ACQUIRE,
                                         __HIP_MEMORY_SCOPE_AGENT) < k + 1)
                    __builtin_amdgcn_s_sleep(2);
                if (k >= 4) {
                    while (__hip_atomic_load(&flags[2], __ATOMIC_RELAXED,
                                             __HIP_MEMORY_SCOPE_AGENT) < k - 3)
                        __builtin_amdgcn_s_sleep(2);
                }
            }
            __builtin_amdgcn_s_waitcnt(0xC07F);
            __builtin_amdgcn_s_barrier();
            const unsigned short* hb = hbuf + (size_t)k * 16 * 1024;
            float* dst = xw1 + (size_t)(k & 3) * 65536;
#pragma unroll 2
            for (int nt = 0; nt < 8; ++nt) {
                const int tl = nt * 2 + (col >> 3);
                const unsigned short* src = hb + tl * 1024 + b * 128 + quad * 8;
                short8 bfr[4];
#pragma unroll
                for (int c = 0; c < 4; ++c) bfr[c] = *(const short8*)&src[c * 32];
                f32x4 acc[4] = {};
#pragma unroll
                for (int c = 0; c < 4; ++c)
#pragma unroll
                    for (int g = 0; g < 4; ++g)
                        acc[g] = mfma16(afrI[g][c], bfr[c], acc[g]);
#pragma unroll
                for (int g = 0; g < 4; ++g) {
                    f32x4 res;
#pragma unroll
                    for (int e = 0; e < 4; ++e) res[e] = acc[g][e] + biasv[g][e];
                    *(f32x4*)&dst[((tl * 4 + g) * 8 + b) * 128 + w * 16 + quad * 4] = res;
                }
            }
            __builtin_amdgcn_s_waitcnt(0x0F70);  // vmcnt(0) only
            __builtin_amdgcn_s_barrier();
            if (tid == 0)
                __hip_atomic_store(&flags[1], k + 1, __ATOMIC_RELEASE,
                                   __HIP_MEMORY_SCOPE_AGENT);
        }
        return;
    }

    for (int i = tid; i < 2 * 16 * 136; i += 512) (&H[0][0])[i] = 0;
    float cst[4] = {0.f, 0.f, 0.f, 0.f};
    const int lane_off = (prA * 8 + b) * 128 + h4;

    if (blockIdx.x == 0) {
        // ---------------- producer: layer 0 ----------------
        short8 afr[4][4];
#pragma unroll
        for (int g = 0; g < 4; ++g) {
            const int row = g * 128 + w * 16 + col;
#pragma unroll
            for (int c = 0; c < 4; ++c) {
                const float* src = Whh0 + row * 128 + c * 32 + quad * 8;
                short8 v;
#pragma unroll
                for (int j = 0; j < 8; ++j) v[j] = (short)bf16_of(src[j]);
                afr[g][c] = v;
            }
        }
        auto xaddr = [&](int t) -> const float* {
            return xw0 + (size_t)t * 4096 + lane_off;
        };
        if (tid == 0) {
            while (__hip_atomic_load(&flags[3], __ATOMIC_ACQUIRE,
                                     __HIP_MEMORY_SCOPE_AGENT) < 1)
                __builtin_amdgcn_s_sleep(2);
        }
        __syncthreads();   // covers H zero too
        f32x4 p0a = *(const f32x4*)xaddr(0);
        f32x4 p1a = *(const f32x4*)(xaddr(0) + 2048);
        f32x4 p0b = *(const f32x4*)xaddr(1);
        f32x4 p1b = *(const f32x4*)(xaddr(1) + 2048);

        for (int c = 0; c < 64; ++c) {
            const int need = (c + 2 < 64) ? c + 2 : 64;
            if (tid == 0) {
                while (__hip_atomic_load(&flags[3], __ATOMIC_ACQUIRE,
                                         __HIP_MEMORY_SCOPE_AGENT) < need)
                    __builtin_amdgcn_s_sleep(2);
            }
            __builtin_amdgcn_s_waitcnt(0xC07F);
            __builtin_amdgcn_s_barrier();
            for (int s = 0; s < 16; s += 2) {
                const int t = c * 16 + s;
                const int t2 = (t + 2 < 1024) ? t + 2 : 1023;
                const int t3 = (t + 3 < 1024) ? t + 3 : 1023;
                {
                    f32x4 xv0 = p0a, xv1 = p1a;
                    p0a = *(const f32x4*)xaddr(t2);
                    p1a = *(const f32x4*)(xaddr(t2) + 2048);
                    lstm_step<0>(&H[0][0], &H[1][0], afr, xv0, xv1, cst, hbuf, t, col, quad, h4, b);
                }
                {
                    f32x4 xv0 = p0b, xv1 = p1b;
                    p0b = *(const f32x4*)xaddr(t3);
                    p1b = *(const f32x4*)(xaddr(t3) + 2048);
                    lstm_step<0>(&H[1][0], &H[0][0], afr, xv0, xv1, cst, hbuf, t + 1, col, quad, h4, b);
                }
            }
            __syncthreads();    // drain hbuf stores across the block
            if (tid == 0)
                __hip_atomic_store(&flags[0], c + 1, __ATOMIC_RELEASE,
                                   __HIP_MEMORY_SCOPE_AGENT);
        }
    } else {
        // ---------------- consumer: layer 1 ----------------
        short8 afr[4][4];
#pragma unroll
        for (int g = 0; g < 4; ++g) {
            const int row = g * 128 + w * 16 + col;
#pragma unroll
            for (int c = 0; c < 4; ++c) {
                const float* src = Whh1 + row * 128 + c * 32 + quad * 8;
                short8 v;
#pragma unroll
                for (int j = 0; j < 8; ++j) v[j] = (short)bf16_of(src[j]);
                afr[g][c] = v;
            }
        }
        __syncthreads();
        auto xaddr = [&](int t) -> const float* {
            return xw1 + (((t >> 4) & 3) * 65536 + (t & 15) * 4096) + lane_off;
        };
        while (__hip_atomic_load(&flags[1], __ATOMIC_ACQUIRE,
                                 __HIP_MEMORY_SCOPE_AGENT) < 2)
            __builtin_amdgcn_s_sleep(2);
        f32x4 p0a = *(const f32x4*)xaddr(0);
        f32x4 p1a = *(const f32x4*)(xaddr(0) + 2048);
        f32x4 p0b = *(const f32x4*)xaddr(1);
        f32x4 p1b = *(const f32x4*)(xaddr(1) + 2048);

        for (int c = 0; c < 64; ++c) {
            if (c > 0) {
                const int target = (c + 2 < 64) ? c + 2 : 64;
                if (tid == 0) {
                    while (__hip_atomic_load(&flags[1], __ATOMIC_ACQUIRE,
                                             __HIP_MEMORY_SCOPE_AGENT) < target)
                        __builtin_amdgcn_s_sleep(2);
                }
                __builtin_amdgcn_s_waitcnt(0xC07F);
                __builtin_amdgcn_s_barrier();
            }
            for (int s = 0; s < 16; s += 2) {
                const int t = c * 16 + s;
                const int t2 = (t + 2 < 1024) ? t + 2 : 1023;
                const int t3 = (t + 3 < 1024) ? t + 3 : 1023;
                {
                    f32x4 xv0 = p0a, xv1 = p1a;
                    p0a = *(const f32x4*)xaddr(t2);
                    p1a = *(const f32x4*)(xaddr(t2) + 2048);
                    lstm_step<1>(&H[0][0], &H[1][0], afr, xv0, xv1, cst, out1b, t, col, quad, h4, b);
                }
                {
                    f32x4 xv0 = p0b, xv1 = p1b;
                    p0b = *(const f32x4*)xaddr(t3);
                    p1b = *(const f32x4*)(xaddr(t3) + 2048);
                    lstm_step<1>(&H[1][0], &H[0][0], afr, xv0, xv1, cst, out1b, t + 1, col, quad, h4, b);
                }
            }
            __syncthreads();   // drain out1b stores before publishing chunk
            if (tid == 0)
                __hip_atomic_store(&flags[2], c + 1, __ATOMIC_RELEASE,
                                   __HIP_MEMORY_SCOPE_AGENT);
        }
    }
}

// ---------------------------------------------------------------------------
extern "C" void kernel_launch(void* const* d_in, const int* in_sizes, int n_in,
                              void* d_out, int out_size, void* d_ws, size_t ws_size,
                              hipStream_t stream)
{
    (void)in_sizes; (void)n_in; (void)out_size; (void)ws_size;
    const float* nf    = (const float*)d_in[0];
    const float* adj   = (const float*)d_in[1];
    const float* g1W   = (const float*)d_in[3];
    const float* g1b   = (const float*)d_in[4];
    const float* g1aW  = (const float*)d_in[5];
    const float* g1ab  = (const float*)d_in[6];
    const float* g2W   = (const float*)d_in[7];
    const float* g2b   = (const float*)d_in[8];
    const float* g2aW  = (const float*)d_in[9];
    const float* g2ab  = (const float*)d_in[10];
    const float* g3W   = (const float*)d_in[11];
    const float* g3b   = (const float*)d_in[12];
    const float* g3aW  = (const float*)d_in[13];
    const float* g3ab  = (const float*)d_in[14];
    const float* l0Wih = (const float*)d_in[15];
    const float* l0Whh = (const float*)d_in[16];
    const float* l0bih = (const float*)d_in[17];
    const float* l0bhh = (const float*)d_in[18];
    const float* l1Wih = (const float*)d_in[19];
    const float* l1Whh = (const float*)d_in[20];
    const float* l1bih = (const float*)d_in[21];
    const float* l1bhh = (const float*)d_in[22];
    const float* opW1 = (const float*)d_in[23];
    const float* opb1 = (const float*)d_in[24];
    const float* opW2 = (const float*)d_in[25];
    const float* opb2 = (const float*)d_in[26];
    const float* paW1 = (const float*)d_in[27];
    const float* pab1 = (const float*)d_in[28];
    const float* paW2 = (const float*)d_in[29];
    const float* pab2 = (const float*)d_in[30];
    const float* skW1 = (const float*)d_in[31];
    const float* skb1 = (const float*)d_in[32];
    const float* skW2 = (const float*)d_in[33];
    const float* skb2 = (const float*)d_in[34];
    const float* noW1 = (const float*)d_in[35];
    const float* nob1 = (const float*)d_in[36];
    const float* noW2 = (const float*)d_in[37];
    const float* nob2 = (const float*)d_in[38];

    float* out = (float*)d_out;
    float* ws = (float*)d_ws;
    float* bufH  = ws;                       // [0, 1048576)
    float* bufX  = ws + 1048576;             // gnn ping / later hbuf
    float* bufH3 = ws + 2097152;             // gnn3 out
    unsigned short* bufT = (unsigned short*)(ws + 3145728);  // hT, -> 3670016
    float* siB  = ws + 3670016;              // 8192
    float* sjB  = ws + 3678208;              // 8192
    float* xw0  = ws + 3686400;              // 4194304 -> 7880704
    float* xw1  = ws + 7880704;              // 262144  -> 8142848
    int*  flags = (int*)(ws + 8142848);      // 8 ints (pad to 16 floats)
    unsigned short* WT = (unsigned short*)(ws + 8142864);     // 131072 shorts
    unsigned short* Wih0T = (unsigned short*)(ws + 8208400);  // 65536 shorts
    unsigned short* out1b = (unsigned short*)(ws + 8241168);  // 1048576 shorts
    unsigned short* hbuf = (unsigned short*)bufX;             // 2 MB

    unsigned short* opW1T = WT;
    unsigned short* paW1T = WT + 16384;
    unsigned short* skW1T = WT + 32768;
    unsigned short* noW1T = WT + 49152;
    unsigned short* opW2T = WT + 65536;
    unsigned short* paW2T = WT + 73728;
    unsigned short* skW2T = WT + 106496;
    unsigned short* noW2T = WT + 122880;

    auto gemm = [&](const float* A, const float* B, const float* bias, float* C,
                    int M, int N, int K, int RELU) {
        dim3 g(N / 64, M / 64);
        gemm_f32<<<g, dim3(256), 0, stream>>>(A, B, bias, C, M, N, K, RELU);
    };

    // ---- prep (head weight transposes + Wih0 bf16 + flag zero)
    PrepArgs pargs;
    pargs.src[0] = opW1; pargs.dst[0] = opW1T; pargs.N[0] = 128;
    pargs.src[1] = paW1; pargs.dst[1] = paW1T; pargs.N[1] = 128;
    pargs.src[2] = skW1; pargs.dst[2] = skW1T; pargs.N[2] = 128;
    pargs.src[3] = noW1; pargs.dst[3] = noW1T; pargs.N[3] = 128;
    pargs.src[4] = opW2; pargs.dst[4] = opW2T; pargs.N[4] = 64;
    pargs.src[5] = paW2; pargs.dst[5] = paW2T; pargs.N[5] = 256;
    pargs.src[6] = skW2; pargs.dst[6] = skW2T; pargs.N[6] = 128;
    pargs.src[7] = noW2; pargs.dst[7] = noW2T; pargs.N[7] = 64;
    prep_k<<<10, 256, 0, stream>>>(pargs, l0Wih, Wih0T, flags);

    // ---- GNN layer 1 (din=64, relu)
    gemm(nf, g1W, g1b, bufH, 8192, 128, 64, 0);
    aux_k<<<dim3(16, 8), 256, 0, stream>>>(bufH, g1aW, siB, sjB, bufT);
    gnn_agg<<<dim3(16, 8), 256, 0, stream>>>(adj, bufT, siB, sjB, g1ab, bufX, 1);
    // ---- GNN layer 2 (relu)
    gemm(bufX, g2W, g2b, bufH, 8192, 128, 128, 0);
    aux_k<<<dim3(16, 8), 256, 0, stream>>>(bufH, g2aW, siB, sjB, bufT);
    gnn_agg<<<dim3(16, 8), 256, 0, stream>>>(adj, bufT, siB, sjB, g2ab, bufX, 1);
    // ---- GNN layer 3 (no relu) -> bufH3
    gemm(bufX, g3W, g3b, bufH, 8192, 128, 128, 0);
    aux_k<<<dim3(16, 8), 256, 0, stream>>>(bufH, g3aW, siB, sjB, bufT);
    gnn_agg<<<dim3(16, 8), 256, 0, stream>>>(adj, bufT, siB, sjB, g3ab, bufH3, 0);

    // ---- pipelined LSTM + fused xw0 build + fused heads
    HeadArgs ha;
    ha.W1T[0] = opW1T; ha.b1[0] = opb1; ha.W2T[0] = opW2T; ha.b2[0] = opb2;
    ha.outp[0] = out + 0;
    ha.W1T[1] = paW1T; ha.b1[1] = pab1; ha.W2T[1] = paW2T; ha.b2[1] = pab2;
    ha.outp[1] = out + 524288;
    ha.W1T[2] = skW1T; ha.b1[2] = skb1; ha.W2T[2] = skW2T; ha.b2[2] = skb2;
    ha.outp[2] = out + 2621440;
    ha.W1T[3] = noW1T; ha.b1[3] = nob1; ha.W2T[3] = noW2T; ha.b2[3] = nob2;
    ha.outp[3] = out + 3670016;
    lstm_pipe<<<12, 512, 0, stream>>>(xw0, Wih0T, l0bih, l0bhh, l0Whh,
                                      l1Wih, l1Whh, l1bih, l1bhh,
                                      hbuf, xw1, flags, out1b, bufH3, ha);
}

// Round 9
// 1404.332 us; speedup vs baseline: 1.7801x; 1.7801x over previous
//
#include <hip/hip_runtime.h>

typedef __attribute__((ext_vector_type(8))) short short8;
typedef __attribute__((ext_vector_type(4))) float f32x4;
typedef __attribute__((ext_vector_type(2))) float f32x2;
typedef __attribute__((ext_vector_type(4))) unsigned short us4;
typedef __attribute__((ext_vector_type(2))) unsigned int u32x2;

__device__ __forceinline__ unsigned short bf16_of(float f) {
    unsigned u = __builtin_bit_cast(unsigned, f);
    u += 0x7fffu + ((u >> 16) & 1u);   // RNE
    return (unsigned short)(u >> 16);
}
__device__ __forceinline__ unsigned bf16pk(float a, float b) {
    return (unsigned)bf16_of(a) | ((unsigned)bf16_of(b) << 16);
}
__device__ __forceinline__ float fexp2(float x) { return __builtin_amdgcn_exp2f(x); }
__device__ __forceinline__ float frcp(float x) { return __builtin_amdgcn_rcpf(x); }
__device__ __forceinline__ float sigm(float x) { return frcp(1.f + fexp2(-1.44269504f * x)); }
__device__ __forceinline__ float tanh_f(float x) {
    float e = fexp2(2.88539008f * x);   // e^(2x)
    return 1.f - 2.f * frcp(e + 1.f);
}
__device__ __forceinline__ f32x4 mfma16(short8 a, short8 b, f32x4 c) {
    return __builtin_amdgcn_mfma_f32_16x16x32_bf16(a, b, c, 0, 0, 0);
}
// DPP cross-lane within 16-lane rows. row_shr:8 -> lane i gets lane i-8;
// row_shl:8 -> lane i gets lane i+8 (bound_ctrl: OOB reads 0).
__device__ __forceinline__ float dpp_shr8(float x) {
    return __builtin_bit_cast(float, __builtin_amdgcn_update_dpp(
        0, __builtin_bit_cast(int, x), 0x118, 0xF, 0xF, true));
}
__device__ __forceinline__ float dpp_shl8(float x) {
    return __builtin_bit_cast(float, __builtin_amdgcn_update_dpp(
        0, __builtin_bit_cast(int, x), 0x108, 0xF, 0xF, true));
}

// ---------------------------------------------------------------------------
// Generic fp32 GEMM: C[M,N] = A[M,K] @ B (+bias) (optional relu).
// BT=1: B is [N,K] row-major (use B^T). PACK=1: write in LSTM pack layout
//   (m = b*1024+t, n = pr*128+h  ->  C[((t*4+pr)*8+b)*128 + h]).
// NOTE (round-8 lesson): xw0 MUST be produced by a completed kernel before
// lstm_pipe launches. Producing it concurrently from another block forces
// agent-scope acquire/release on the producer's chunk loop -> cross-XCD L2
// invalidate/writeback every 16 steps -> ~2x pipe slowdown (r8: 1070->2193us).
__global__ __launch_bounds__(256) void gemm_f32(
    const float* __restrict__ A, const float* __restrict__ B,
    const float* __restrict__ bias, float* __restrict__ C,
    int M, int N, int K, int BT, int RELU, int PACK)
{
    __shared__ float As[64][33];
    __shared__ float Bs[32][68];
    const int tid = threadIdx.x;
    const int tx = tid & 15, ty = tid >> 4;
    const int m0 = blockIdx.y * 64, n0 = blockIdx.x * 64;
    float acc[4][4];
#pragma unroll
    for (int i = 0; i < 4; ++i)
#pragma unroll
        for (int j = 0; j < 4; ++j) acc[i][j] = 0.f;

    for (int k0 = 0; k0 < K; k0 += 32) {
        __syncthreads();
        {   // stage A 64x32
            const int r = tid >> 2, kk = (tid & 3) * 8;
            const float* src = A + (size_t)(m0 + r) * K + k0 + kk;
            f32x4 v0 = *(const f32x4*)src;
            f32x4 v1 = *(const f32x4*)(src + 4);
#pragma unroll
            for (int e = 0; e < 4; ++e) { As[r][kk + e] = v0[e]; As[r][kk + 4 + e] = v1[e]; }
        }
        if (!BT) {  // stage B 32x64
            const int kk = tid >> 3, nn = (tid & 7) * 8;
            const float* src = B + (size_t)(k0 + kk) * N + n0 + nn;
            f32x4 v0 = *(const f32x4*)src;
            f32x4 v1 = *(const f32x4*)(src + 4);
#pragma unroll
            for (int e = 0; e < 4; ++e) { Bs[kk][nn + e] = v0[e]; Bs[kk][nn + 4 + e] = v1[e]; }
        } else {    // B given [N,K]: transpose-stage
            const int n = tid >> 2, kk = (tid & 3) * 8;
            const float* src = B + (size_t)(n0 + n) * K + k0 + kk;
            f32x4 v0 = *(const f32x4*)src;
            f32x4 v1 = *(const f32x4*)(src + 4);
#pragma unroll
            for (int e = 0; e < 4; ++e) { Bs[kk + e][n] = v0[e]; Bs[kk + 4 + e][n] = v1[e]; }
        }
        __syncthreads();
#pragma unroll 8
        for (int k = 0; k < 32; ++k) {
            float a0 = As[ty * 4 + 0][k], a1 = As[ty * 4 + 1][k];
            float a2 = As[ty * 4 + 2][k], a3 = As[ty * 4 + 3][k];
            f32x4 bv = *(const f32x4*)&Bs[k][tx * 4];
#pragma unroll
            for (int j = 0; j < 4; ++j) {
                acc[0][j] += a0 * bv[j]; acc[1][j] += a1 * bv[j];
                acc[2][j] += a2 * bv[j]; acc[3][j] += a3 * bv[j];
            }
        }
    }
    f32x4 bv = {};
    if (bias != nullptr) bv = *(const f32x4*)&bias[n0 + tx * 4];
#pragma unroll
    for (int i = 0; i < 4; ++i) {
        f32x4 res = {};
#pragma unroll
        for (int j = 0; j < 4; ++j) {
            float v = acc[i][j] + bv[j];
            if (RELU) v = fmaxf(v, 0.f);
            res[j] = v;
        }
        const int m = m0 + ty * 4 + i;
        if (!PACK) {
            *(f32x4*)&C[(size_t)m * N + n0 + tx * 4] = res;
        } else {
            const int b = m >> 10, t = m & 1023;
            const int n = n0 + tx * 4;
            const int pr = n >> 7, h = n & 127;
            *(f32x4*)&C[(((size_t)t * 4 + pr) * 8 + b) * 128 + h] = res;
        }
    }
}

// ---------------------------------------------------------------------------
// Fused sisj + transpose: per (jt, b) tile of h:
//   si/sj[b*1024+jt*64+r] = h-row dot aW halves; hT[b][d][j] = bf16(h[b][j][d])
__global__ __launch_bounds__(256) void aux_k(
    const float* __restrict__ h, const float* __restrict__ aW,
    float* __restrict__ si, float* __restrict__ sj,
    unsigned short* __restrict__ hT)
{
    __shared__ float t[64][129];
    __shared__ float awl[256];
    const int jt = blockIdx.x, b = blockIdx.y;
    const int tid = threadIdx.x;
    awl[tid] = aW[tid];
    {
        const int r = tid >> 2, c8 = (tid & 3) * 32;
        const float* src = h + ((size_t)b * 1024 + jt * 64 + r) * 128 + c8;
#pragma unroll
        for (int e = 0; e < 32; e += 4)
            *(f32x4*)&t[r][c8 + e] = *(const f32x4*)(src + e);
    }
    __syncthreads();
    if (tid < 64) {
        float sjp = 0.f, sip = 0.f;
#pragma unroll 8
        for (int d = 0; d < 128; ++d) {
            float v = t[tid][d];
            sjp += v * awl[d];
            sip += v * awl[128 + d];
        }
        si[b * 1024 + jt * 64 + tid] = sip;
        sj[b * 1024 + jt * 64 + tid] = sjp;
    }
    {
        const int d = tid >> 1, j0 = (tid & 1) * 32;
        unsigned short* dst = hT + ((size_t)b * 128 + d) * 1024 + jt * 64 + j0;
#pragma unroll
        for (int j = 0; j < 32; j += 4) {
            u32x2 o;
            o[0] = bf16pk(t[j0 + j][d], t[j0 + j + 1][d]);
            o[1] = bf16pk(t[j0 + j + 2][d], t[j0 + j + 3][d]);
            *(u32x2*)(dst + j) = o;
        }
    }
}

// ---------------------------------------------------------------------------
// out[b,i,d] = sum_j sigmoid(si[i]+sj[j]+ab)*adj[b,i,j]*h[b,j,d]  (opt relu)
__global__ __launch_bounds__(256) void gnn_agg(
    const float* __restrict__ adj, const unsigned short* __restrict__ hT,
    const float* __restrict__ si, const float* __restrict__ sj,
    const float* __restrict__ abp, float* __restrict__ out, int RELU)
{
    __shared__ __align__(16) unsigned short Alds[64 * 40];   // [i][j] stride 40
    __shared__ __align__(16) unsigned short Blds[128 * 40];  // [d][j] stride 40
    const int b = blockIdx.y, it = blockIdx.x;
    const int i0 = it * 64;
    const int tid = threadIdx.x, lane = tid & 63, w = tid >> 6;
    const int quad = lane >> 4, col = lane & 15;
    const float ab = abp[0];
    const float* adjb = adj + (size_t)b * 1024 * 1024;
    const unsigned short* hTb = hT + (size_t)b * 128 * 1024;
    const float* sjb = sj + b * 1024;

    f32x4 acc[8] = {};
    const int ar_ = tid >> 2, ash = (tid & 3) * 8;
    const int br_ = tid >> 1, bsh = (tid & 1) * 16;
    const float sii = si[b * 1024 + i0 + ar_] + ab;

    for (int j0 = 0; j0 < 1024; j0 += 32) {
        __syncthreads();
        {   // stage A: att tile 64x32 (computed on the fly)
            const float* ar = adjb + (size_t)(i0 + ar_) * 1024 + j0 + ash;
            f32x4 av0 = *(const f32x4*)ar;
            f32x4 av1 = *(const f32x4*)(ar + 4);
            float s[8];
#pragma unroll
            for (int e = 0; e < 4; ++e) {
                s[e]     = sigm(sii + sjb[j0 + ash + e])     * av0[e];
                s[4 + e] = sigm(sii + sjb[j0 + ash + 4 + e]) * av1[e];
            }
            u32x2 o0 = {bf16pk(s[0], s[1]), bf16pk(s[2], s[3])};
            u32x2 o1 = {bf16pk(s[4], s[5]), bf16pk(s[6], s[7])};
            unsigned short* al = Alds + ar_ * 40 + ash;
            *(u32x2*)&al[0] = o0;
            *(u32x2*)&al[4] = o1;
        }
        {   // stage B: hT rows d=0..127, 32 j's
            const unsigned short* bsrc = hTb + (size_t)br_ * 1024 + j0 + bsh;
            unsigned short* bl = Blds + br_ * 40 + bsh;
            *(short8*)&bl[0] = *(const short8*)&bsrc[0];
            *(short8*)&bl[8] = *(const short8*)&bsrc[8];
        }
        __syncthreads();
        short8 af = *(const short8*)&Alds[(w * 16 + col) * 40 + quad * 8];
#pragma unroll
        for (int nt = 0; nt < 8; ++nt) {
            short8 bf = *(const short8*)&Blds[(nt * 16 + col) * 40 + quad * 8];
            acc[nt] = mfma16(af, bf, acc[nt]);
        }
    }
    const int ibase = i0 + w * 16 + quad * 4;
#pragma unroll
    for (int nt = 0; nt < 8; ++nt) {
        const int d = nt * 16 + col;
#pragma unroll
        for (int r = 0; r < 4; ++r) {
            float v = acc[nt][r];
            if (RELU) v = fmaxf(v, 0.f);
            out[((size_t)b * 1024 + ibase + r) * 128 + d] = v;
        }
    }
}

// ---------------------------------------------------------------------------
// Prep: transpose+bf16 the 8 head weight matrices to [n][k]; bsum=bih0+bhh0;
// zero flags. 9 blocks.
struct PrepArgs {
    const float* src[8];
    unsigned short* dst[8];
    int N[8];
};
__global__ __launch_bounds__(256) void prep_k(
    PrepArgs pa, const float* bih0, const float* bhh0,
    float* bsum, int* flags)
{
    const int m = blockIdx.x;
    const int tid = threadIdx.x;
    if (m < 8) {
        const float* src = pa.src[m];
        unsigned short* dst = pa.dst[m];
        const int N = pa.N[m];
        const int n0 = tid >> 4, kc = (tid & 15) * 8;
        for (int n = n0; n < N; n += 16) {
            unsigned o[4];
#pragma unroll
            for (int e = 0; e < 8; e += 2)
                o[e >> 1] = bf16pk(src[(size_t)(kc + e) * N + n],
                                   src[(size_t)(kc + e + 1) * N + n]);
            *(u32x2*)&dst[n * 128 + kc] = *(u32x2*)&o[0];
            *(u32x2*)&dst[n * 128 + kc + 4] = *(u32x2*)&o[2];
        }
    } else {
        bsum[tid] = bih0[tid] + bhh0[tid];
        bsum[tid + 256] = bih0[tid + 256] + bhh0[tid + 256];
        if (tid < 8) flags[tid] = 0;
    }
}

// ---------------------------------------------------------------------------
// 11-block lstm_pipe: 2-layer LSTM pipeline + fused MLP heads (round-7 layout).
//  block 0 producer : layer-0 recurrence -> bf16 hbuf; flags[0] += 1/16 steps
//  block 1 helper   : xw1(chunk) = h0 @ Wih1^T + bias -> 4-slot ring; flags[1]
//  block 2 consumer : layer-1 recurrence off ring -> bf16 out1b; flags[2]
//  blocks 3-10      : head workers: `no` head (bufH3) immediately; op/pa/sk
//                     per 128-row strip as flags[2] publishes chunks.
// Per-step barrier = lgkmcnt(0)-only waitcnt + s_barrier builtins (vmcnt
// prefetches stay outstanding). Flag waits tid0-guarded. The PRODUCER has no
// acquires in its loop (round-8 lesson).

struct HeadArgs {
    const unsigned short* W1T[4];
    const float* b1[4];
    const unsigned short* W2T[4];
    const float* b2[4];
    float* outp[4];       // op, pa, sk, no
};

__device__ __forceinline__ void lstm_epilogue(
    const f32x4 accs[4], f32x4 xv0, f32x4 xv1, float* cst, float* hv, bool lo)
{
    float t0[4], t1[4];
#pragma unroll
    for (int i = 0; i < 4; ++i) {
        float P0 = 0.5f * ((lo ? accs[0][i] : dpp_shr8(accs[1][i])) + xv0[i]);
        float P1r = (lo ? accs[2][i] : dpp_shr8(accs[3][i])) + xv1[i];
        float P1 = lo ? P1r : 0.5f * P1r;
        t0[i] = tanh_f(P0);
        t1[i] = tanh_f(P1);
    }
    float c2[4], og[4];
#pragma unroll
    for (int i = 0; i < 4; ++i) {
        float ig = 0.5f + 0.5f * t0[i];
        float fg = 0.5f + 0.5f * dpp_shl8(t0[i]);
        float gg = t1[i];
        og[i] = 0.5f + 0.5f * dpp_shl8(t1[i]);
        c2[i] = fg * cst[i] + ig * gg;
        cst[i] = c2[i];
    }
    float pc0 = lo ? c2[0] : dpp_shr8(c2[1]);
    float pc1 = lo ? c2[2] : dpp_shr8(c2[3]);
    float tc0 = tanh_f(pc0), tc1 = tanh_f(pc1);
    float th[4] = {tc0, dpp_shl8(tc0), tc1, dpp_shl8(tc1)};
#pragma unroll
    for (int i = 0; i < 4; ++i) hv[i] = og[i] * th[i];
}

// SINK=0: bf16 hbuf [t*1024 + b*128 + h]; SINK=1: bf16 out1b [(t*8+b)*128 + h]
template <int SINK>
__device__ __forceinline__ void lstm_step(
    unsigned short* Hc, unsigned short* Hn, const short8 afr[4][4],
    f32x4 xv0, f32x4 xv1, float* cst, unsigned short* __restrict__ sink,
    int t, int col, int quad, int h4, int b)
{
    short8 bfr[4];
#pragma unroll
    for (int c = 0; c < 4; ++c)
        bfr[c] = *(const short8*)&Hc[col * 136 + c * 32 + quad * 8];
    f32x4 accs[4] = {};
#pragma unroll
    for (int c = 0; c < 4; ++c)
#pragma unroll
        for (int g = 0; g < 4; ++g)
            accs[g] = mfma16(afr[g][c], bfr[c], accs[g]);

    const bool lo = (col < 8);
    float hv[4];
    lstm_epilogue(accs, xv0, xv1, cst, hv, lo);
    if (lo) {
        u32x2 hb = {bf16pk(hv[0], hv[1]), bf16pk(hv[2], hv[3])};
        *(u32x2*)&Hn[b * 136 + h4] = hb;
        if (SINK == 0)
            *(u32x2*)(sink + (size_t)t * 1024 + b * 128 + h4) = hb;
        else
            *(u32x2*)(sink + ((size_t)t * 8 + b) * 128 + h4) = hb;
    }
    __builtin_amdgcn_s_waitcnt(0xC07F);  // lgkmcnt(0) only
    __builtin_amdgcn_s_barrier();
}

// One 128-row strip of a 2-layer MLP head (8 waves / 512 threads).
template <int A32, int LROWS>
__device__ void head_strip(
    const void* __restrict__ Asrc, int row0,
    const unsigned short* __restrict__ W1T, const float* __restrict__ b1,
    const unsigned short* __restrict__ W2T, const float* __restrict__ b2,
    float* __restrict__ outp, int dout, unsigned short* A2, int tid)
{
    const int lane = tid & 63, w = tid >> 6;
    const int quad = lane >> 4, col = lane & 15;
    const int mrow = w * 16 + col;
    f32x4 acc[8] = {};
#pragma unroll
    for (int kc = 0; kc < 4; ++kc) {
        short8 af;
        if (A32) {
            const float* s = (const float*)Asrc + (size_t)(row0 + mrow) * 128 + kc * 32 + quad * 8;
            f32x4 v0 = *(const f32x4*)s, v1 = *(const f32x4*)(s + 4);
            short8 v;
#pragma unroll
            for (int j = 0; j < 4; ++j) {
                v[j] = (short)bf16_of(v0[j]);
                v[4 + j] = (short)bf16_of(v1[j]);
            }
            af = v;
        } else {
            af = *(const short8*)((const unsigned short*)Asrc +
                                  (size_t)(row0 + mrow) * 128 + kc * 32 + quad * 8);
        }
#pragma unroll
        for (int nt = 0; nt < 8; ++nt) {
            short8 bf = *(const short8*)&W1T[(nt * 16 + col) * 128 + kc * 32 + quad * 8];
            acc[nt] = mfma16(af, bf, acc[nt]);
        }
    }
    float b1v[8];
#pragma unroll
    for (int nt = 0; nt < 8; ++nt) b1v[nt] = b1[nt * 16 + col];
    __syncthreads();
#pragma unroll
    for (int nt = 0; nt < 8; ++nt)
#pragma unroll
        for (int i = 0; i < 4; ++i) {
            const int mm = w * 16 + quad * 4 + i;
            A2[mm * 136 + nt * 16 + col] = bf16_of(fmaxf(acc[nt][i] + b1v[nt], 0.f));
        }
    __syncthreads();
    const int ntiles = dout >> 4;
    for (int np = 0; np < ntiles; np += 8) {
        const int nts = (ntiles - np < 8) ? ntiles - np : 8;
        f32x4 acc2[8] = {};
#pragma unroll
        for (int kc = 0; kc < 4; ++kc) {
            short8 a2f = *(const short8*)&A2[mrow * 136 + kc * 32 + quad * 8];
            for (int nt = 0; nt < nts; ++nt) {
                short8 bf = *(const short8*)&W2T[((np + nt) * 16 + col) * 128 + kc * 32 + quad * 8];
                acc2[nt] = mfma16(a2f, bf, acc2[nt]);
            }
        }
        for (int nt = 0; nt < nts; ++nt) {
            const int n = (np + nt) * 16 + col;
            const float bb = b2[n];
#pragma unroll
            for (int i = 0; i < 4; ++i) {
                const int r = row0 + w * 16 + quad * 4 + i;
                size_t off;
                if (LROWS) off = ((size_t)(r & 7) * 1024 + (r >> 3)) * dout + n;
                else       off = (size_t)r * dout + n;
                outp[off] = acc2[nt][i] + bb;
            }
        }
    }
}

__global__ __launch_bounds__(512) void lstm_pipe(
    const float* __restrict__ xw0, const float* __restrict__ Whh0,
    const float* __restrict__ Wih1, const float* __restrict__ Whh1,
    const float* __restrict__ bih1, const float* __restrict__ bhh1,
    unsigned short* __restrict__ hbuf, float* __restrict__ xw1,
    int* __restrict__ flags, unsigned short* __restrict__ out1b,
    const float* __restrict__ bufH3, HeadArgs ha)
{
    __shared__ __align__(16) unsigned short H[2][16 * 136];
    __shared__ __align__(16) unsigned short A2[128 * 136];
    const int tid = threadIdx.x;
    const int lane = tid & 63;
    const int w = tid >> 6;
    const int quad = lane >> 4;
    const int col = lane & 15;
    const int b = col & 7;
    const int prA = col >> 3;
    const int h4 = w * 16 + quad * 4;

    if (blockIdx.x >= 3) {
        // ---------------- head workers ----------------
        const int wid = blockIdx.x - 3;   // 0..7
        for (int s = wid; s < 64; s += 8)
            head_strip<1, 0>(bufH3, s * 128, ha.W1T[3], ha.b1[3],
                             ha.W2T[3], ha.b2[3], ha.outp[3], 64, A2, tid);
        for (int s = wid; s < 64; s += 8) {
            if (tid == 0) {
                while (__hip_atomic_load(&flags[2], __ATOMIC_ACQUIRE,
                                         __HIP_MEMORY_SCOPE_AGENT) < s + 1)
                    __builtin_amdgcn_s_sleep(16);
            }
            __syncthreads();
            head_strip<0, 1>(out1b, s * 128, ha.W1T[0], ha.b1[0],
                             ha.W2T[0], ha.b2[0], ha.outp[0], 64, A2, tid);
            head_strip<0, 1>(out1b, s * 128, ha.W1T[1], ha.b1[1],
                             ha.W2T[1], ha.b2[1], ha.outp[1], 256, A2, tid);
            head_strip<0, 1>(out1b, s * 128, ha.W1T[2], ha.b1[2],
                             ha.W2T[2], ha.b2[2], ha.outp[2], 128, A2, tid);
        }
        return;
    }

    if (blockIdx.x == 1) {
        // ---------------- helper: xw1 = h0 @ Wih1^T + bias ----------------
        short8 afrI[4][4];
        f32x4 biasv[4];
#pragma unroll
        for (int g = 0; g < 4; ++g) {
            const int row = g * 128 + w * 16 + col;
#pragma unroll
            for (int c = 0; c < 4; ++c) {
                const float* src = Wih1 + row * 128 + c * 32 + quad * 8;
                short8 v;
#pragma unroll
                for (int j = 0; j < 8; ++j) v[j] = (short)bf16_of(src[j]);
                afrI[g][c] = v;
            }
            const int rb = g * 128 + w * 16 + quad * 4;
            f32x4 b1 = *(const f32x4*)&bih1[rb];
            f32x4 b2 = *(const f32x4*)&bhh1[rb];
#pragma unroll
            for (int e = 0; e < 4; ++e) biasv[g][e] = b1[e] + b2[e];
        }
        for (int k = 0; k < 64; ++k) {
            if (tid == 0) {
                while (__hip_atomic_load(&flags[0], __ATOMIC_ACQUIRE,
                                         __HIP_MEMORY_SCOPE_AGENT) < k + 1)
                    __builtin_amdgcn_s_sleep(2);
                if (k >= 4) {
                    while (__hip_atomic_load(&flags[2], __ATOMIC_RELAXED,
                                             __HIP_MEMORY_SCOPE_AGENT) < k - 3)
                        __builtin_amdgcn_s_sleep(2);
                }
            }
            __builtin_amdgcn_s_waitcnt(0xC07F);
            __builtin_amdgcn_s_barrier();
            const unsigned short* hb = hbuf + (size_t)k * 16 * 1024;
            float* dst = xw1 + (size_t)(k & 3) * 65536;
#pragma unroll 2
            for (int nt = 0; nt < 8; ++nt) {
                const int tl = nt * 2 + (col >> 3);
                const unsigned short* src = hb + tl * 1024 + b * 128 + quad * 8;
                short8 bfr[4];
#pragma unroll
                for (int c = 0; c < 4; ++c) bfr[c] = *(const short8*)&src[c * 32];
                f32x4 acc[4] = {};
#pragma unroll
                for (int c = 0; c < 4; ++c)
#pragma unroll
                    for (int g = 0; g < 4; ++g)
                        acc[g] = mfma16(afrI[g][c], bfr[c], acc[g]);
#pragma unroll
                for (int g = 0; g < 4; ++g) {
                    f32x4 res;
#pragma unroll
                    for (int e = 0; e < 4; ++e) res[e] = acc[g][e] + biasv[g][e];
                    *(f32x4*)&dst[((tl * 4 + g) * 8 + b) * 128 + w * 16 + quad * 4] = res;
                }
            }
            __builtin_amdgcn_s_waitcnt(0x0F70);  // vmcnt(0) only
            __builtin_amdgcn_s_barrier();
            if (tid == 0)
                __hip_atomic_store(&flags[1], k + 1, __ATOMIC_RELEASE,
                                   __HIP_MEMORY_SCOPE_AGENT);
        }
        return;
    }

    for (int i = tid; i < 2 * 16 * 136; i += 512) (&H[0][0])[i] = 0;
    float cst[4] = {0.f, 0.f, 0.f, 0.f};
    const int lane_off = (prA * 8 + b) * 128 + h4;

    if (blockIdx.x == 0) {
        // ---------------- producer: layer 0 (no acquires in loop!) --------
        short8 afr[4][4];
#pragma unroll
        for (int g = 0; g < 4; ++g) {
            const int row = g * 128 + w * 16 + col;
#pragma unroll
            for (int c = 0; c < 4; ++c) {
                const float* src = Whh0 + row * 128 + c * 32 + quad * 8;
                short8 v;
#pragma unroll
                for (int j = 0; j < 8; ++j) v[j] = (short)bf16_of(src[j]);
                afr[g][c] = v;
            }
        }
        const float* xp = xw0 + lane_off;
        f32x4 p0a = *(const f32x4*)(xp);
        f32x4 p1a = *(const f32x4*)(xp + 2048);
        f32x4 p0b = *(const f32x4*)(xp + 4096);
        f32x4 p1b = *(const f32x4*)(xp + 6144);
        xp += 8192;
        __syncthreads();

        for (int t = 0; t < 1024; t += 2) {
            const float* xr = (t == 1022) ? xp - 8192 : xp;
            {
                f32x4 xv0 = p0a, xv1 = p1a;
                p0a = *(const f32x4*)(xr);
                p1a = *(const f32x4*)(xr + 2048);
                lstm_step<0>(&H[0][0], &H[1][0], afr, xv0, xv1, cst, hbuf, t, col, quad, h4, b);
            }
            {
                f32x4 xv0 = p0b, xv1 = p1b;
                p0b = *(const f32x4*)(xr + 4096);
                p1b = *(const f32x4*)(xr + 6144);
                lstm_step<0>(&H[1][0], &H[0][0], afr, xv0, xv1, cst, hbuf, t + 1, col, quad, h4, b);
            }
            xp += 8192;
            if ((t & 14) == 14) {   // chunk (t>>4) complete
                __syncthreads();    // drain hbuf stores across the block
                if (tid == 0)
                    __hip_atomic_store(&flags[0], (t >> 4) + 1, __ATOMIC_RELEASE,
                                       __HIP_MEMORY_SCOPE_AGENT);
            }
        }
    } else {
        // ---------------- consumer: layer 1 ----------------
        short8 afr[4][4];
#pragma unroll
        for (int g = 0; g < 4; ++g) {
            const int row = g * 128 + w * 16 + col;
#pragma unroll
            for (int c = 0; c < 4; ++c) {
                const float* src = Whh1 + row * 128 + c * 32 + quad * 8;
                short8 v;
#pragma unroll
                for (int j = 0; j < 8; ++j) v[j] = (short)bf16_of(src[j]);
                afr[g][c] = v;
            }
        }
        __syncthreads();
        auto xaddr = [&](int t) -> const float* {
            return xw1 + (((t >> 4) & 3) * 65536 + (t & 15) * 4096) + lane_off;
        };
        while (__hip_atomic_load(&flags[1], __ATOMIC_ACQUIRE,
                                 __HIP_MEMORY_SCOPE_AGENT) < 2)
            __builtin_amdgcn_s_sleep(2);
        f32x4 p0a = *(const f32x4*)xaddr(0);
        f32x4 p1a = *(const f32x4*)(xaddr(0) + 2048);
        f32x4 p0b = *(const f32x4*)xaddr(1);
        f32x4 p1b = *(const f32x4*)(xaddr(1) + 2048);

        for (int c = 0; c < 64; ++c) {
            if (c > 0) {
                const int target = (c + 2 < 64) ? c + 2 : 64;
                if (tid == 0) {
                    while (__hip_atomic_load(&flags[1], __ATOMIC_ACQUIRE,
                                             __HIP_MEMORY_SCOPE_AGENT) < target)
                        __builtin_amdgcn_s_sleep(2);
                }
                __builtin_amdgcn_s_waitcnt(0xC07F);
                __builtin_amdgcn_s_barrier();
            }
            for (int s = 0; s < 16; s += 2) {
                const int t = c * 16 + s;
                const int t2 = (t + 2 < 1024) ? t + 2 : 1023;
                const int t3 = (t + 3 < 1024) ? t + 3 : 1023;
                {
                    f32x4 xv0 = p0a, xv1 = p1a;
                    p0a = *(const f32x4*)xaddr(t2);
                    p1a = *(const f32x4*)(xaddr(t2) + 2048);
                    lstm_step<1>(&H[0][0], &H[1][0], afr, xv0, xv1, cst, out1b, t, col, quad, h4, b);
                }
                {
                    f32x4 xv0 = p0b, xv1 = p1b;
                    p0b = *(const f32x4*)xaddr(t3);
                    p1b = *(const f32x4*)(xaddr(t3) + 2048);
                    lstm_step<1>(&H[1][0], &H[0][0], afr, xv0, xv1, cst, out1b, t + 1, col, quad, h4, b);
                }
            }
            __syncthreads();   // drain out1b stores before publishing chunk
            if (tid == 0)
                __hip_atomic_store(&flags[2], c + 1, __ATOMIC_RELEASE,
                                   __HIP_MEMORY_SCOPE_AGENT);
        }
    }
}

// ---------------------------------------------------------------------------
extern "C" void kernel_launch(void* const* d_in, const int* in_sizes, int n_in,
                              void* d_out, int out_size, void* d_ws, size_t ws_size,
                              hipStream_t stream)
{
    (void)in_sizes; (void)n_in; (void)out_size; (void)ws_size;
    const float* nf    = (const float*)d_in[0];
    const float* adj   = (const float*)d_in[1];
    const float* g1W   = (const float*)d_in[3];
    const float* g1b   = (const float*)d_in[4];
    const float* g1aW  = (const float*)d_in[5];
    const float* g1ab  = (const float*)d_in[6];
    const float* g2W   = (const float*)d_in[7];
    const float* g2b   = (const float*)d_in[8];
    const float* g2aW  = (const float*)d_in[9];
    const float* g2ab  = (const float*)d_in[10];
    const float* g3W   = (const float*)d_in[11];
    const float* g3b   = (const float*)d_in[12];
    const float* g3aW  = (const float*)d_in[13];
    const float* g3ab  = (const float*)d_in[14];
    const float* l0Wih = (const float*)d_in[15];
    const float* l0Whh = (const float*)d_in[16];
    const float* l0bih = (const float*)d_in[17];
    const float* l0bhh = (const float*)d_in[18];
    const float* l1Wih = (const float*)d_in[19];
    const float* l1Whh = (const float*)d_in[20];
    const float* l1bih = (const float*)d_in[21];
    const float* l1bhh = (const float*)d_in[22];
    const float* opW1 = (const float*)d_in[23];
    const float* opb1 = (const float*)d_in[24];
    const float* opW2 = (const float*)d_in[25];
    const float* opb2 = (const float*)d_in[26];
    const float* paW1 = (const float*)d_in[27];
    const float* pab1 = (const float*)d_in[28];
    const float* paW2 = (const float*)d_in[29];
    const float* pab2 = (const float*)d_in[30];
    const float* skW1 = (const float*)d_in[31];
    const float* skb1 = (const float*)d_in[32];
    const float* skW2 = (const float*)d_in[33];
    const float* skb2 = (const float*)d_in[34];
    const float* noW1 = (const float*)d_in[35];
    const float* nob1 = (const float*)d_in[36];
    const float* noW2 = (const float*)d_in[37];
    const float* nob2 = (const float*)d_in[38];

    float* out = (float*)d_out;
    float* ws = (float*)d_ws;
    float* bufH  = ws;                       // [0, 1048576)
    float* bufX  = ws + 1048576;             // gnn ping / later hbuf
    float* bufH3 = ws + 2097152;             // gnn3 out (node head input)
    unsigned short* bufT = (unsigned short*)(ws + 3145728);  // hT -> 3670016
    float* siB  = ws + 3670016;              // 8192
    float* sjB  = ws + 3678208;              // 8192
    float* bsum = ws + 3686400;              // 512
    float* xw0  = ws + 3687424;              // 4194304 -> 7881728
    float* xw1  = ws + 7881728;              // 262144  -> 8143872 (4-slot ring)
    int*  flags = (int*)(ws + 8143872);      // 8 ints
    unsigned short* WT = (unsigned short*)(ws + 8143880);    // 131072 shorts
    unsigned short* out1b = (unsigned short*)(ws + 8209416); // 1048576 shorts
    unsigned short* hbuf = (unsigned short*)bufX;            // 2 MB

    unsigned short* opW1T = WT;
    unsigned short* paW1T = WT + 16384;
    unsigned short* skW1T = WT + 32768;
    unsigned short* noW1T = WT + 49152;
    unsigned short* opW2T = WT + 65536;
    unsigned short* paW2T = WT + 73728;
    unsigned short* skW2T = WT + 106496;
    unsigned short* noW2T = WT + 122880;

    auto gemm = [&](const float* A, const float* B, const float* bias, float* C,
                    int M, int N, int K, int BT, int RELU, int PACK = 0) {
        dim3 g(N / 64, M / 64);
        gemm_f32<<<g, dim3(256), 0, stream>>>(A, B, bias, C, M, N, K, BT, RELU, PACK);
    };

    // ---- prep (head weight transposes + bsum + flag zero)
    PrepArgs pargs;
    pargs.src[0] = opW1; pargs.dst[0] = opW1T; pargs.N[0] = 128;
    pargs.src[1] = paW1; pargs.dst[1] = paW1T; pargs.N[1] = 128;
    pargs.src[2] = skW1; pargs.dst[2] = skW1T; pargs.N[2] = 128;
    pargs.src[3] = noW1; pargs.dst[3] = noW1T; pargs.N[3] = 128;
    pargs.src[4] = opW2; pargs.dst[4] = opW2T; pargs.N[4] = 64;
    pargs.src[5] = paW2; pargs.dst[5] = paW2T; pargs.N[5] = 256;
    pargs.src[6] = skW2; pargs.dst[6] = skW2T; pargs.N[6] = 128;
    pargs.src[7] = noW2; pargs.dst[7] = noW2T; pargs.N[7] = 64;
    prep_k<<<9, 256, 0, stream>>>(pargs, l0bih, l0bhh, bsum, flags);

    // ---- GNN layer 1 (din=64, relu)
    gemm(nf, g1W, g1b, bufH, 8192, 128, 64, 0, 0);
    aux_k<<<dim3(16, 8), 256, 0, stream>>>(bufH, g1aW, siB, sjB, bufT);
    gnn_agg<<<dim3(16, 8), 256, 0, stream>>>(adj, bufT, siB, sjB, g1ab, bufX, 1);
    // ---- GNN layer 2 (relu)
    gemm(bufX, g2W, g2b, bufH, 8192, 128, 128, 0, 0);
    aux_k<<<dim3(16, 8), 256, 0, stream>>>(bufH, g2aW, siB, sjB, bufT);
    gnn_agg<<<dim3(16, 8), 256, 0, stream>>>(adj, bufT, siB, sjB, g2ab, bufX, 1);
    // ---- GNN layer 3 (no relu) -> bufH3
    gemm(bufX, g3W, g3b, bufH, 8192, 128, 128, 0, 0);
    aux_k<<<dim3(16, 8), 256, 0, stream>>>(bufH, g3aW, siB, sjB, bufT);
    gnn_agg<<<dim3(16, 8), 256, 0, stream>>>(adj, bufT, siB, sjB, g3ab, bufH3, 0);

    // ---- layer-0 xw in pack layout (bias folded) — completed BEFORE pipe
    gemm(bufH3, l0Wih, bsum, xw0, 8192, 512, 128, 1, 0, 1);

    // ---- pipelined LSTM + fused heads
    HeadArgs ha;
    ha.W1T[0] = opW1T; ha.b1[0] = opb1; ha.W2T[0] = opW2T; ha.b2[0] = opb2;
    ha.outp[0] = out + 0;
    ha.W1T[1] = paW1T; ha.b1[1] = pab1; ha.W2T[1] = paW2T; ha.b2[1] = pab2;
    ha.outp[1] = out + 524288;
    ha.W1T[2] = skW1T; ha.b1[2] = skb1; ha.W2T[2] = skW2T; ha.b2[2] = skb2;
    ha.outp[2] = out + 2621440;
    ha.W1T[3] = noW1T; ha.b1[3] = nob1; ha.W2T[3] = noW2T; ha.b2[3] = nob2;
    ha.outp[3] = out + 3670016;
    lstm_pipe<<<11, 512, 0, stream>>>(xw0, l0Whh, l1Wih, l1Whh, l1bih, l1bhh,
                                      hbuf, xw1, flags, out1b, bufH3, ha);
}